// Round 6
// baseline (717.042 us; speedup 1.0000x reference)
//
#include <hip/hip_runtime.h>
#include <cstdint>

typedef short short8 __attribute__((ext_vector_type(8)));
typedef float f32x16 __attribute__((ext_vector_type(16)));

// Problem constants
#define NB 4
#define NN 4096
#define ND 576
#define BIGI 0x7FFFFFFF
#define NSLICE 8

// ws layout: A_hi (bf16) [b][tile32][kc18][512 chunks of 16B] = 9437184 shorts,
// then A_lo same size; then (float units):
#define INVN_OFF 9437184
#define CANDV_OFF 9439488
// CANDV: 4*8*4096*3 = 393216 floats -> ends at 9832704
#define CANDI_OFF 9832704
// CANDI: 393216 u16 = 196608 float-equiv -> total 10029312 floats = 40.1 MB
// Chunk swizzle (baked into layout): chunk g = r*4 + c', source chunk
// c = c' ^ ((r>>1)&3), i.e. source k-span = c*8..c*8+7 of row r.

#define MFMA __builtin_amdgcn_mfma_f32_32x32x16_bf16

__device__ __forceinline__ unsigned short f2bf(float f) {
    unsigned u = __float_as_uint(f);
    u += 0x7FFFu + ((u >> 16) & 1u);   // round-to-nearest-even
    return (unsigned short)(u >> 16);
}

__device__ __forceinline__ void gload_lds16(const void* g, void* l) {
    __builtin_amdgcn_global_load_lds(
        (const __attribute__((address_space(1))) void*)g,
        (__attribute__((address_space(3))) void*)l, 16, 0, 0);
}

// Exact jax top_k comparator: bigger value wins; tie -> smaller index wins.
__device__ __forceinline__ void insert_cmp(float v, int m,
    float& v0, int& i0, float& v1, int& i1, float& v2, int& i2) {
    bool beat2 = (v > v2) || (v == v2 && m < i2);
    if (beat2) {
        bool beat1 = (v > v1) || (v == v1 && m < i1);
        if (beat1) {
            v2 = v1; i2 = i1;
            bool beat0 = (v > v0) || (v == v0 && m < i0);
            if (beat0) { v1 = v0; i1 = i0; v0 = v; i0 = m; }
            else       { v1 = v;  i1 = m; }
        } else { v2 = v; i2 = m; }
    }
}

// Kernel 1: per-(b,c) windowed sums of x^2 -> inv norms for the 9 kernel offsets.
__global__ __launch_bounds__(64) void norm_kernel(const float* __restrict__ x,
                                                  float* __restrict__ ws) {
    const int bc = blockIdx.x;          // b*64 + c
    const int lane = threadIdx.x;       // = column w
    const float* xp = x + ((size_t)bc << 12);
    float colsum = 0.f, v0 = 0.f, v63 = 0.f;
    for (int h = 0; h < 64; ++h) {
        const float val = xp[(h << 6) + lane];
        const float sq = val * val;
        colsum += sq;
        if (h == 0)  v0 = sq;
        if (h == 63) v63 = sq;
    }
    float total = colsum, row0 = v0, row63 = v63;
    #pragma unroll
    for (int o = 32; o > 0; o >>= 1) {
        total += __shfl_xor(total, o);
        row0  += __shfl_xor(row0, o);
        row63 += __shfl_xor(row63, o);
    }
    const float col0  = __shfl(colsum, 0);
    const float col63 = __shfl(colsum, 63);
    const float c00 = __shfl(v0, 0),  c0e = __shfl(v0, 63);
    const float ce0 = __shfl(v63, 0), cee = __shfl(v63, 63);
    if (lane < 9) {
        const int dh = lane / 3 - 1, dw = lane % 3 - 1;
        float S = total;
        if (dh == 1)  S -= row0;
        if (dh == -1) S -= row63;
        if (dw == 1)  S -= col0;
        if (dw == -1) S -= col63;
        if (dh == 1  && dw == 1)  S += c00;
        if (dh == 1  && dw == -1) S += c0e;
        if (dh == -1 && dw == 1)  S += ce0;
        if (dh == -1 && dw == -1) S += cee;
        float nrm = fmaxf(sqrtf(S), 1e-12f);
        ws[INVN_OFF + bc * 9 + lane] = 1.0f / nrm;
    }
}

// Kernel 2: split-bf16 materialization with baked chunk swizzle.
// blockIdx = (b*32+nt)*18+kc. Region = 512 chunks of 16B (8 bf16).
__global__ __launch_bounds__(256) void mat_kernel(const float* __restrict__ x,
                                                  float* __restrict__ ws) {
    const int bi = blockIdx.x;             // 2304 blocks
    const int b = bi / 576;
    const int rem = bi - b * 576;
    const int nt = rem / 18;
    const int kc = rem - nt * 18;
    unsigned short* AH = (unsigned short*)ws;
    unsigned short* AL = AH + 9437184;
    const float* invn = ws + INVN_OFF + b * 576;
    const int tid = threadIdx.x;
    #pragma unroll
    for (int hf2 = 0; hf2 < 2; ++hf2) {
        const int g = tid + hf2 * 256;     // output chunk 0..511
        const int row = g >> 2, cp = g & 3;
        const int c = cp ^ ((row >> 1) & 3);    // source chunk (swizzle)
        const int k0 = c * 8;
        const int n = nt * 128 + row;
        const int h = n >> 6, wc = n & 63;
        union { unsigned short us[8]; float4 f4; } uh, ul;
        #pragma unroll
        for (int j = 0; j < 8; ++j) {
            const int d = kc * 32 + k0 + j;
            const int ch = d / 9;
            const int p = d - ch * 9;
            const int r = h + p / 3 - 1, s2 = wc + p % 3 - 1;
            float val = 0.f;
            if ((unsigned)r < 64u && (unsigned)s2 < 64u)
                val = x[((size_t)(b * 64 + ch) << 12) + (r << 6) + s2];
            val *= invn[d];
            const unsigned short hb = f2bf(val);
            const float hfv = __uint_as_float(((unsigned)hb) << 16);
            const unsigned short lb = f2bf(val - hfv);
            uh.us[j] = hb; ul.us[j] = lb;
        }
        ((float4*)AH)[(size_t)bi * 512 + g] = uh.f4;
        ((float4*)AL)[(size_t)bi * 512 + g] = ul.f4;
    }
}

__device__ __forceinline__ short8 ldfrag(const short* p) {
    union { short8 s8; float4 f4; } u;
    u.f4 = *(const float4*)p;
    return u.s8;
}

// Kernel 3: R = A^T A via split-bf16 MFMA (hh + hl + lh), fused top-3.
// Grid 1024 = b(4) x nt(32) x slice(8). Block: 128 n-rows x 512 m-cols
// (2 mt steps of 256). 4 waves, wave tile = 128n x 64m. 48KB LDS -> 3 blocks/CU.
// Staging via global_load_lds (16B, identity lane-ordered copy).
// C/D: m_part = (reg&3)+8*(reg>>2)+4*(lane>>5), n_part = lane&31  [HW-verified r4]
__global__ void __launch_bounds__(256, 2) gram_kernel(float* ws) {
    __shared__ short sm[24576];   // 48KB: AnH(8K) AnL(8K) AmH(16K) AmL(16K) bytes
    const int bx = blockIdx.x;
    const int b = bx >> 8;
    const int nt = (bx >> 3) & 31;
    const int s = bx & 7;
    const int tid = threadIdx.x;
    const int w = tid >> 6, lane = tid & 63;
    const int l31 = lane & 31, kh2 = lane >> 5;

    const unsigned short* AH = (const unsigned short*)ws;
    const unsigned short* AL = AH + 9437184;

    // LDS region bases (shorts)
    const int AnH = 0, AnL = 4096, AmH = 8192, AmL = 16384;   // Am: t0 then t1 (+4096)
    const int nRegBase = (b * 32 + nt) * 18;

    float t0v[4], t1v[4], t2v[4];
    int   t0i[4], t1i[4], t2i[4];
    #pragma unroll
    for (int i = 0; i < 4; ++i) {
        t0v[i] = t1v[i] = t2v[i] = -INFINITY;
        t0i[i] = t1i[i] = t2i[i] = BIGI;
    }

    // per-lane frag LDS offsets (shorts), swizzled chunk addressing:
    // frag(row, c) at row*32 + (c ^ ((row>>1)&3))*8, c = kh2 + 2h
    int aoff[2][2];      // [mi][h] Am (within 16K region incl. tile select)
    int boff[4][2];      // [ni][h] An
    #pragma unroll
    for (int mi = 0; mi < 2; ++mi)
        #pragma unroll
        for (int h = 0; h < 2; ++h) {
            const int row = w * 64 + mi * 32 + l31;      // 0..255
            const int rl = row & 127, rt = row >> 7;
            const int c = kh2 + 2 * h;
            aoff[mi][h] = rt * 4096 + rl * 32 + (c ^ ((rl >> 1) & 3)) * 8;
        }
    #pragma unroll
    for (int ni = 0; ni < 4; ++ni)
        #pragma unroll
        for (int h = 0; h < 2; ++h) {
            const int row = ni * 32 + l31;               // 0..127
            const int c = kh2 + 2 * h;
            boff[ni][h] = row * 32 + (c ^ ((row >> 1) & 3)) * 8;
        }

    for (int mt = 0; mt < 2; ++mt) {
        const int p = s * 2 + mt;                    // 256-col pair index 0..15
        const int mReg0 = (b * 32 + 2 * p) * 18;
        const int mReg1 = mReg0 + 18;

        f32x16 acc[2][4];
        #pragma unroll
        for (int mi = 0; mi < 2; ++mi)
            #pragma unroll
            for (int ni = 0; ni < 4; ++ni)
                #pragma unroll
                for (int e = 0; e < 16; ++e) acc[mi][ni][e] = 0.f;

        for (int kc = 0; kc < 18; ++kc) {
            __syncthreads();
            // stage 6 x 8KB regions; per wave 2 instrs/region, 1KB each
            {
                const int lo0 = (w * 2) * 512, lo1 = (w * 2 + 1) * 512;   // LDS shorts
                const int go0 = lo0 + lane * 8, go1 = lo1 + lane * 8;     // global shorts
                const unsigned short* gAnH = AH + (size_t)(nRegBase + kc) * 4096;
                const unsigned short* gAnL = AL + (size_t)(nRegBase + kc) * 4096;
                const unsigned short* gM0H = AH + (size_t)(mReg0 + kc) * 4096;
                const unsigned short* gM1H = AH + (size_t)(mReg1 + kc) * 4096;
                const unsigned short* gM0L = AL + (size_t)(mReg0 + kc) * 4096;
                const unsigned short* gM1L = AL + (size_t)(mReg1 + kc) * 4096;
                gload_lds16(gAnH + go0, sm + AnH + lo0);
                gload_lds16(gAnH + go1, sm + AnH + lo1);
                gload_lds16(gAnL + go0, sm + AnL + lo0);
                gload_lds16(gAnL + go1, sm + AnL + lo1);
                gload_lds16(gM0H + go0, sm + AmH + lo0);
                gload_lds16(gM0H + go1, sm + AmH + lo1);
                gload_lds16(gM1H + go0, sm + AmH + 4096 + lo0);
                gload_lds16(gM1H + go1, sm + AmH + 4096 + lo1);
                gload_lds16(gM0L + go0, sm + AmL + lo0);
                gload_lds16(gM0L + go1, sm + AmL + lo1);
                gload_lds16(gM1L + go0, sm + AmL + 4096 + lo0);
                gload_lds16(gM1L + go1, sm + AmL + 4096 + lo1);
            }
            __syncthreads();
            #pragma unroll
            for (int h = 0; h < 2; ++h) {
                short8 amh[2], aml[2];
                #pragma unroll
                for (int mi = 0; mi < 2; ++mi) {
                    amh[mi] = ldfrag(sm + AmH + aoff[mi][h]);
                    aml[mi] = ldfrag(sm + AmL + aoff[mi][h]);
                }
                #pragma unroll
                for (int ni = 0; ni < 4; ++ni) {
                    const short8 bh = ldfrag(sm + AnH + boff[ni][h]);
                    const short8 bl = ldfrag(sm + AnL + boff[ni][h]);
                    #pragma unroll
                    for (int mi = 0; mi < 2; ++mi) {
                        acc[mi][ni] = MFMA(amh[mi], bh, acc[mi][ni], 0, 0, 0);
                        acc[mi][ni] = MFMA(amh[mi], bl, acc[mi][ni], 0, 0, 0);
                        acc[mi][ni] = MFMA(aml[mi], bh, acc[mi][ni], 0, 0, 0);
                    }
                }
            }
        }
        // fold acc into per-lane top-3 (per ni; n = ni*32 + l31)
        const int mbase = p * 256 + w * 64 + kh2 * 4;
        #pragma unroll
        for (int ni = 0; ni < 4; ++ni)
            #pragma unroll
            for (int mi = 0; mi < 2; ++mi)
                #pragma unroll
                for (int v = 0; v < 16; ++v) {
                    const int m = mbase + mi * 32 + (v & 3) + 8 * (v >> 2);
                    insert_cmp(acc[mi][ni][v], m,
                               t0v[ni], t0i[ni], t1v[ni], t1i[ni], t2v[ni], t2i[ni]);
                }
    }

    // merge the two kh2 halves (same n, disjoint m) via shfl
    #pragma unroll
    for (int ni = 0; ni < 4; ++ni) {
        const float pv0 = __shfl_xor(t0v[ni], 32);
        const float pv1 = __shfl_xor(t1v[ni], 32);
        const float pv2 = __shfl_xor(t2v[ni], 32);
        const int pi0 = __shfl_xor(t0i[ni], 32);
        const int pi1 = __shfl_xor(t1i[ni], 32);
        const int pi2 = __shfl_xor(t2i[ni], 32);
        insert_cmp(pv0, pi0, t0v[ni], t0i[ni], t1v[ni], t1i[ni], t2v[ni], t2i[ni]);
        insert_cmp(pv1, pi1, t0v[ni], t0i[ni], t1v[ni], t1i[ni], t2v[ni], t2i[ni]);
        insert_cmp(pv2, pi2, t0v[ni], t0i[ni], t1v[ni], t1i[ni], t2v[ni], t2i[ni]);
    }
    // cross-wave merge through LDS (each wave owns a 64-wide m slice)
    __syncthreads();
    float* cv = (float*)sm;              // [w4][ni4][l32][3] floats
    int*   ci = (int*)sm + 1536;
    if (kh2 == 0) {
        #pragma unroll
        for (int ni = 0; ni < 4; ++ni) {
            const int base = ((w * 4 + ni) * 32 + l31) * 3;
            cv[base] = t0v[ni]; cv[base + 1] = t1v[ni]; cv[base + 2] = t2v[ni];
            ci[base] = t0i[ni]; ci[base + 1] = t1i[ni]; ci[base + 2] = t2i[ni];
        }
    }
    __syncthreads();
    if (tid < 128) {
        const int ni = tid >> 5, l = tid & 31;
        float v0 = -INFINITY, v1 = -INFINITY, v2 = -INFINITY;
        int i0 = BIGI, i1 = BIGI, i2 = BIGI;
        #pragma unroll
        for (int w2 = 0; w2 < 4; ++w2) {
            const int base = ((w2 * 4 + ni) * 32 + l) * 3;
            #pragma unroll
            for (int j = 0; j < 3; ++j)
                insert_cmp(cv[base + j], ci[base + j], v0, i0, v1, i1, v2, i2);
        }
        const int n_local = ni * 32 + l;
        const size_t o = ((size_t)(b * NSLICE + s) * NN + nt * 128 + n_local) * 3;
        ws[CANDV_OFF + o] = v0; ws[CANDV_OFF + o + 1] = v1; ws[CANDV_OFF + o + 2] = v2;
        unsigned short* wi = (unsigned short*)(ws + CANDI_OFF);
        wi[o] = (unsigned short)i0; wi[o + 1] = (unsigned short)i1; wi[o + 2] = (unsigned short)i2;
    }
}

// Kernel 4: merge slice candidates -> global top-3; 27-way attention. One wave per n.
__global__ __launch_bounds__(256) void attn_kernel(const float* __restrict__ x,
                                                   const float* __restrict__ ws,
                                                   float* __restrict__ out) {
    const int wid = threadIdx.x >> 6;
    const int lane = threadIdx.x & 63;
    const int gw = blockIdx.x * 4 + wid;   // 0..16383
    const int b = gw >> 12;
    const int n = gw & 4095;

    float v0 = -INFINITY, v1 = -INFINITY, v2 = -INFINITY;
    int i0 = BIGI, i1 = BIGI, i2 = BIGI;
    const unsigned short* wi = (const unsigned short*)(ws + CANDI_OFF);
    #pragma unroll
    for (int s = 0; s < NSLICE; ++s) {
        const size_t o = ((size_t)(b * NSLICE + s) * NN + n) * 3;
        #pragma unroll
        for (int j = 0; j < 3; ++j)
            insert_cmp(ws[CANDV_OFF + o + j], (int)wi[o + j], v0, i0, v1, i1, v2, i2);
    }
    const int idx3[3] = {i0, i1, i2};

    // per-lane feature meta for d = a*64 + lane  (torch reshape: K[...,a,c'] = xu[a*64+c'])
    int cc[9], dhh[9], dww[9];
    float inr[9];
    #pragma unroll
    for (int a = 0; a < 9; ++a) {
        const int d = a * 64 + lane;
        const int c = d / 9;
        const int p = d - c * 9;
        cc[a] = c; dhh[a] = p / 3 - 1; dww[a] = p - (p / 3) * 3 - 1;
        inr[a] = ws[INVN_OFF + b * ND + d];
    }
    const float q = x[((size_t)(b * 64 + lane) << 12) + n];

    float rv[27], sc[27];
    #pragma unroll
    for (int k = 0; k < 3; ++k) {
        const int m = idx3[k];
        const int hm = m >> 6, wm = m & 63;
        #pragma unroll
        for (int a = 0; a < 9; ++a) {
            const int r = hm + dhh[a], s2 = wm + dww[a];
            float val = 0.f;
            if ((unsigned)r < 64u && (unsigned)s2 < 64u)
                val = x[((size_t)(b * 64 + cc[a]) << 12) + (r << 6) + s2];
            const float rr = val * inr[a];
            rv[k * 9 + a] = rr;
            float t = q * rr;
            #pragma unroll
            for (int o2 = 32; o2 > 0; o2 >>= 1) t += __shfl_xor(t, o2);
            sc[k * 9 + a] = t * 0.125f;   // / sqrt(64)
        }
    }
    float mx = -INFINITY;
    #pragma unroll
    for (int u = 0; u < 27; ++u) mx = fmaxf(mx, sc[u]);
    float sum = 0.f;
    #pragma unroll
    for (int u = 0; u < 27; ++u) { const float e = expf(sc[u] - mx); sc[u] = e; sum += e; }
    const float inv = 1.0f / sum;
    float o = 0.f;
    #pragma unroll
    for (int u = 0; u < 27; ++u) o += sc[u] * rv[u];
    out[((size_t)gw << 6) + lane] = o * inv;
}

extern "C" void kernel_launch(void* const* d_in, const int* in_sizes, int n_in,
                              void* d_out, int out_size, void* d_ws, size_t ws_size,
                              hipStream_t stream) {
    (void)in_sizes; (void)n_in; (void)out_size; (void)ws_size;
    const float* x = (const float*)d_in[0];
    float* ws = (float*)d_ws;
    float* out = (float*)d_out;

    hipLaunchKernelGGL(norm_kernel, dim3(NB * 64), dim3(64), 0, stream, x, ws);
    hipLaunchKernelGGL(mat_kernel, dim3(2304), dim3(256), 0, stream, x, ws);
    hipLaunchKernelGGL(gram_kernel, dim3(1024), dim3(256), 0, stream, ws);
    hipLaunchKernelGGL(attn_kernel, dim3(4096), dim3(256), 0, stream, x, ws, out);
}